// Round 12
// baseline (157.377 us; speedup 1.0000x reference)
//
#include <hip/hip_runtime.h>
#include <hip/hip_bf16.h>
#include <cmath>

#define BZ 8
#define PZ 8192
#define FZ 768
#define FI 256
#define M_TOTAL (BZ * PZ)   // 65536
#define BM 128
#define BK 64
#define NKT (FZ / BK)       // 12
#define NB_TILE (128 * BK)  // 8192 elements = 16 KB per (nb, t) B-tile

typedef __bf16 bf16_t;
typedef __bf16 bf16x8 __attribute__((ext_vector_type(8)));
typedef float f32x4 __attribute__((ext_vector_type(4)));

#define AS1 __attribute__((address_space(1)))
#define AS3 __attribute__((address_space(3)))
#define FENCE asm volatile("" ::: "memory")

// ---------------- pack V_w / U_w into per-(nb,t)-tiled, pre-swizzled bf16 ----
// packed col pr = 32*j + 16*u + r  <->  orig o = 16*j + r  (u: 0=V, 1=U)
// Tile (nb = pr>>7, t): contiguous 16 KB; within it, row prl = pr&127,
// 16B-slot `slot` stored at phys slot^(prl&7)  ->  a LINEAR DMA copy into LDS
// yields the bank-conflict-free swizzled layout directly. (R6-R9 proven)
__global__ void pack_weights(const float* __restrict__ Vw,
                             const float* __restrict__ Uw,
                             bf16_t* __restrict__ Wc) {
    int pr = blockIdx.x;                 // 0..511
    int j = pr >> 5, u = (pr >> 4) & 1, r = pr & 15;
    const float* src = (u ? Uw : Vw) + (size_t)(j * 16 + r) * FZ;
    int nb = pr >> 7, prl = pr & 127;
    for (int k = threadIdx.x; k < FZ; k += blockDim.x) {
        int t = k >> 6, slot = (k >> 3) & 7, jj = k & 7;
        Wc[(size_t)(nb * NKT + t) * NB_TILE + prl * 64 + ((slot ^ (prl & 7)) * 8 + jj)]
            = (bf16_t)src[k];
    }
}

// ---------------- fused GEMM + gate + w-reduce -> partial logits ----------------
// 2048 blocks x 256 threads (4 waves, 2wm x 2wn; wave tile 64x64 = 4fm x 4fn of
// 16x16x32 frags). R9 skeleton (single As 16KB + double Bs 32KB, 2 barriers per
// tile, 3 blocks/CU) with A-PREFETCH DEPTH 2:
//   areg[2] ping-pong; issueA(t+2) at iter t -> writeA(t+1) consumes regs
//   issued a FULL TILE earlier (implicit vmcnt wait becomes free).
//   Drain: counted vmcnt(8) (drains B(t+1), leaves A(t+2) in flight across the
//   barrier -- R10-proven count pattern); vmcnt(0) at tail.
__global__ __launch_bounds__(256, 3)
void gemm_gate(const float* __restrict__ x, const bf16_t* __restrict__ Wc,
               const float* __restrict__ Vb, const float* __restrict__ Ub,
               const float* __restrict__ ww, float* __restrict__ part) {
    __shared__ bf16_t As[BM * BK] __attribute__((aligned(16)));      // 16 KB
    __shared__ bf16_t Bs[2][128 * BK] __attribute__((aligned(16)));  // 2x16 KB

    // XCD-aware remap (R2-proven): 4 n-blocks of one m-tile share bid%8 -> same
    // XCD L2 -> x fetched from HBM ~once.
    const int bid = blockIdx.x;
    const int nb = (bid >> 3) & 3;
    const int mt = (bid & 7) | ((bid >> 5) << 3);    // 0..511
    const int tid = threadIdx.x;
    const int l = tid & 63, wv = tid >> 6;
    const int wm = wv >> 1, wn = wv & 1;             // 2M x 2N waves
    const int row0 = mt * BM;

    f32x4 acc[4][4] = {};                            // [fm][fn]
    float4 areg[2][8];                               // depth-2 A staging regs
    const bf16_t* WcB = Wc + (size_t)nb * NKT * NB_TILE;

    // A: issue 8 x dwordx4 fp32 loads for tile t into areg[p] (coalesced)
    auto issueA = [&](int t, int p) {
        #pragma unroll
        for (int i = 0; i < 4; ++i) {
            int sidx = tid + i * 256;            // 0..1023
            int row = sidx >> 3, sl = sidx & 7;
            const float* gp = x + (size_t)(row0 + row) * FZ + t * BK + sl * 8;
            areg[p][2 * i]     = *(const float4*)gp;
            areg[p][2 * i + 1] = *(const float4*)(gp + 4);
        }
    };
    // A: cvt bf16 + swizzled LDS write (slot^(row&7)); compiler waits on areg[p]
    auto writeA = [&](int p) {
        #pragma unroll
        for (int i = 0; i < 4; ++i) {
            int sidx = tid + i * 256;
            int row = sidx >> 3, sl = sidx & 7;
            float4 f0 = areg[p][2 * i], f1 = areg[p][2 * i + 1];
            bf16x8 v;
            v[0] = (bf16_t)f0.x; v[1] = (bf16_t)f0.y; v[2] = (bf16_t)f0.z; v[3] = (bf16_t)f0.w;
            v[4] = (bf16_t)f1.x; v[5] = (bf16_t)f1.y; v[6] = (bf16_t)f1.z; v[7] = (bf16_t)f1.w;
            *(bf16x8*)&As[row * 64 + (sl ^ (row & 7)) * 8] = v;
        }
    };
    // B: 4 x 1KB linear DMA per wave from pre-swizzled Wc tile
    auto issueB = [&](int t, int buf) {
        const bf16_t* src = WcB + (size_t)t * NB_TILE + wv * 2048 + l * 8;
        bf16_t* dst = &Bs[buf][wv * 2048];
        #pragma unroll
        for (int c = 0; c < 4; ++c)
            __builtin_amdgcn_global_load_lds(
                (const AS1 void*)(src + c * 512),
                (AS3 void*)(dst + c * 512), 16, 0, 0);
    };
    auto compute = [&](int buf) {
        #pragma unroll
        for (int kk = 0; kk < 2; ++kk) {
            int sg = kk * 4 + (l >> 4);          // 16B k-slot group (0-conflict)
            bf16x8 af[4], bfr[4];
            #pragma unroll
            for (int fm = 0; fm < 4; ++fm) {
                int row = wm * 64 + fm * 16 + (l & 15);
                af[fm] = *(const bf16x8*)&As[row * 64 + ((sg ^ (row & 7)) * 8)];
            }
            #pragma unroll
            for (int fn = 0; fn < 4; ++fn) {
                int col = wn * 64 + fn * 16 + (l & 15);
                bfr[fn] = *(const bf16x8*)&Bs[buf][col * 64 + ((sg ^ (col & 7)) * 8)];
            }
            #pragma unroll
            for (int fm = 0; fm < 4; ++fm)
                #pragma unroll
                for (int fn = 0; fn < 4; ++fn)
                    acc[fm][fn] = __builtin_amdgcn_mfma_f32_16x16x32_bf16(
                        af[fm], bfr[fn], acc[fm][fn], 0, 0, 0);
        }
    };

    // ---- prologue: A(0),B(0),A(1) in flight; stage As(0); drain A(0)+B(0) ----
    issueA(0, 0); FENCE;
    issueB(0, 0); FENCE;
    issueA(1, 1); FENCE;
    writeA(0);                           // implicit wait drains A(0) (oldest 8)
    asm volatile("s_waitcnt vmcnt(8) lgkmcnt(0)" ::: "memory");  // drain B(0); A(1) flies
    __builtin_amdgcn_sched_barrier(0);
    __builtin_amdgcn_s_barrier();

    #pragma unroll
    for (int t = 0; t < NKT; ++t) {
        const int cur = t & 1;
        // issue order pinned: B(t+1) FIRST (drained next), then A(t+2) (flies)
        if (t + 1 < NKT) { issueB(t + 1, cur ^ 1); FENCE; }
        if (t + 2 < NKT) { issueA(t + 2, t & 1); FENCE; }
        compute(cur);                    // reads As(t), Bs[cur]
        if (t + 1 < NKT) {
            __builtin_amdgcn_s_barrier();    // all waves done reading As(t)
            writeA((t + 1) & 1);             // implicit wait on A(t+1): issued a
                                             // full tile ago -> ~free
            if (t + 2 < NKT)
                // drain B(t+1) [oldest 4 after A(t+1)]; A(t+2)[8] stays in flight
                asm volatile("s_waitcnt vmcnt(8) lgkmcnt(0)" ::: "memory");
            else
                asm volatile("s_waitcnt vmcnt(0) lgkmcnt(0)" ::: "memory");
            __builtin_amdgcn_sched_barrier(0);
            __builtin_amdgcn_s_barrier();    // As(t+1) + Bs[cur^1](t+1) ready
        }
    }

    // ---- epilogue: gate + reduce (HW exp: v_exp_f32) ----
    // C/D 16x16: col = l&15, row = (l>>4)*4 + e. fn pairs (2q,2q+1) hold V/U
    // logits for the SAME orig output o in the SAME lane.
    const int c16 = l & 15;
    float vb[2], ub[2], wf[2];
    #pragma unroll
    for (int q = 0; q < 2; ++q) {
        int o = (nb * 4 + wn * 2 + q) * 16 + c16;
        vb[q] = Vb[o]; ub[q] = Ub[o]; wf[q] = ww[o];
    }
    const int slot = nb * 2 + wn;                // 8 disjoint partial slots
    #pragma unroll
    for (int fm = 0; fm < 4; ++fm) {
        #pragma unroll
        for (int e = 0; e < 4; ++e) {
            float partial = 0.f;
            #pragma unroll
            for (int q = 0; q < 2; ++q) {
                float zv = acc[fm][2 * q][e] + vb[q];
                float zu = acc[fm][2 * q + 1][e] + ub[q];
                float th = 1.f - 2.f / (__expf(2.f * zv) + 1.f);   // tanh(zv)
                float sg = 1.f / (1.f + __expf(-zu));              // sigmoid(zu)
                partial += th * sg * wf[q];
            }
            partial += __shfl_xor(partial, 1);
            partial += __shfl_xor(partial, 2);
            partial += __shfl_xor(partial, 4);
            partial += __shfl_xor(partial, 8);
            if (c16 == 0) {
                int r = row0 + wm * 64 + fm * 16 + (l >> 4) * 4 + e;
                part[(size_t)slot * M_TOTAL + r] = partial;
            }
        }
    }
}

// ---------------- per-bag masked softmax ----------------
__global__ __launch_bounds__(1024)
void softmax_kernel(const float* __restrict__ part, const int* __restrict__ nonpad,
                    float* __restrict__ out) {
    __shared__ float satt[PZ];
    __shared__ float red[16];
    int b = blockIdx.x;
    int np = nonpad[b];
    int tid = threadIdx.x;

    for (int p = tid; p < PZ; p += 1024) {
        float s = 0.f;
        #pragma unroll
        for (int q = 0; q < 8; ++q) s += part[(size_t)q * M_TOTAL + b * PZ + p];
        satt[p] = s;
    }
    __syncthreads();

    float m = -3.4e38f;
    for (int p = tid; p < np; p += 1024) m = fmaxf(m, satt[p]);
    #pragma unroll
    for (int off = 32; off; off >>= 1) m = fmaxf(m, __shfl_xor(m, off));
    if ((tid & 63) == 0) red[tid >> 6] = m;
    __syncthreads();
    m = red[0];
    #pragma unroll
    for (int i = 1; i < 16; ++i) m = fmaxf(m, red[i]);
    __syncthreads();

    float sum = 0.f;
    for (int p = tid; p < np; p += 1024) sum += __expf(satt[p] - m);
    #pragma unroll
    for (int off = 32; off; off >>= 1) sum += __shfl_xor(sum, off);
    if ((tid & 63) == 0) red[tid >> 6] = sum;
    __syncthreads();
    float S = red[0];
    #pragma unroll
    for (int i = 1; i < 16; ++i) S += red[i];
    float inv = 1.f / S;

    for (int p = tid; p < PZ; p += 1024)
        out[b * PZ + p] = (p < np) ? __expf(satt[p] - m) * inv : 0.f;
}

extern "C" void kernel_launch(void* const* d_in, const int* in_sizes, int n_in,
                              void* d_out, int out_size, void* d_ws, size_t ws_size,
                              hipStream_t stream) {
    const float* x    = (const float*)d_in[0];
    const int* nonpad = (const int*)d_in[1];
    const float* V_w  = (const float*)d_in[2];
    const float* V_b  = (const float*)d_in[3];
    const float* U_w  = (const float*)d_in[4];
    const float* U_b  = (const float*)d_in[5];
    const float* w_w  = (const float*)d_in[6];
    // d_in[7] = w_b: uniform logit shift -> softmax-invariant, unused.

    bf16_t* Wc  = (bf16_t*)d_ws;                                  // 768 KB
    float* part = (float*)((char*)d_ws + (size_t)512 * FZ * 2);   // 2 MB
    float* out  = (float*)d_out;

    pack_weights<<<512, 128, 0, stream>>>(V_w, U_w, Wc);
    gemm_gate<<<2048, 256, 0, stream>>>(x, Wc, V_b, U_b, w_w, part);
    softmax_kernel<<<8, 1024, 0, stream>>>(part, nonpad, out);
}

// Round 13
// 154.667 us; speedup vs baseline: 1.0175x; 1.0175x over previous
//
#include <hip/hip_runtime.h>
#include <hip/hip_bf16.h>
#include <cmath>

#define BZ 8
#define PZ 8192
#define FZ 768
#define FI 256
#define M_TOTAL (BZ * PZ)   // 65536
#define BM 256
#define BK 64
#define NKT (FZ / BK)       // 12
#define NB_TILE (128 * BK)  // 8192 elements = 16 KB per (nb, t) B-tile

typedef __bf16 bf16_t;
typedef __bf16 bf16x8 __attribute__((ext_vector_type(8)));
typedef float f32x4 __attribute__((ext_vector_type(4)));

#define AS1 __attribute__((address_space(1)))
#define AS3 __attribute__((address_space(3)))
#define FENCE asm volatile("" ::: "memory")

// ---------------- pack V_w / U_w into per-(nb,t)-tiled, pre-swizzled bf16 ----
// packed col pr = 32*j + 16*u + r  <->  orig o = 16*j + r  (u: 0=V, 1=U)
// Tile (nb = pr>>7, t): contiguous 16 KB; within it, row prl = pr&127,
// 16B-slot `slot` stored at phys slot^(prl&7)  ->  a LINEAR DMA copy into LDS
// yields the bank-conflict-free swizzled layout directly. (R6-R9 proven)
__global__ void pack_weights(const float* __restrict__ Vw,
                             const float* __restrict__ Uw,
                             bf16_t* __restrict__ Wc) {
    int pr = blockIdx.x;                 // 0..511
    int j = pr >> 5, u = (pr >> 4) & 1, r = pr & 15;
    const float* src = (u ? Uw : Vw) + (size_t)(j * 16 + r) * FZ;
    int nb = pr >> 7, prl = pr & 127;
    for (int k = threadIdx.x; k < FZ; k += blockDim.x) {
        int t = k >> 6, slot = (k >> 3) & 7, jj = k & 7;
        Wc[(size_t)(nb * NKT + t) * NB_TILE + prl * 64 + ((slot ^ (prl & 7)) * 8 + jj)]
            = (bf16_t)src[k];
    }
}

// ---------------- fused GEMM + gate + w-reduce -> partial logits ----------------
// 1024 blocks x 512 threads (8 waves = 4M x 2N; wave tile 64x64 = 4fm x 4fn of
// 16x16x32 frags -- per-wave geometry IDENTICAL to R9's 94us kernel). R9
// pipeline verbatim: issue B(t+1) DMA + A(t+1) reg loads before compute(t);
// barrier; writeA; vmcnt(0) drain; barrier. BM=256 doubles rows per block:
// As 32KB + Bs 2x16KB = 64KB LDS -> 2 blocks/CU = 16 waves/CU (vs R9's 12),
// half the blocks, half the total B-DMA traffic.
__global__ __launch_bounds__(512, 4)
void gemm_gate(const float* __restrict__ x, const bf16_t* __restrict__ Wc,
               const float* __restrict__ Vb, const float* __restrict__ Ub,
               const float* __restrict__ ww, float* __restrict__ part) {
    __shared__ bf16_t As[BM * BK] __attribute__((aligned(16)));      // 32 KB
    __shared__ bf16_t Bs[2][128 * BK] __attribute__((aligned(16)));  // 2x16 KB

    // XCD-aware remap (R2-proven): the 4 n-blocks of one m-tile share bid%8
    // -> same XCD L2 -> x fetched from HBM ~once. 1024 blocks, bijective.
    const int bid = blockIdx.x;
    const int nb = (bid >> 3) & 3;
    const int mt = (bid & 7) | ((bid >> 5) << 3);    // 0..255
    const int tid = threadIdx.x;
    const int l = tid & 63, wv = tid >> 6;           // 8 waves
    const int wm = wv >> 1, wn = wv & 1;             // 4M x 2N waves
    const int row0 = mt * BM;

    f32x4 acc[4][4] = {};                            // [fm][fn]
    float4 areg[8];                                  // A(t+1) staging, 32 VGPR
    const bf16_t* WcB = Wc + (size_t)nb * NKT * NB_TILE;

    // A: issue 8 x dwordx4 fp32 loads for tile t (coalesced; rows 0..255)
    auto issueA = [&](int t) {
        #pragma unroll
        for (int i = 0; i < 4; ++i) {
            int sidx = tid + i * 512;            // 0..2047
            int row = sidx >> 3, sl = sidx & 7;
            const float* gp = x + (size_t)(row0 + row) * FZ + t * BK + sl * 8;
            areg[2 * i]     = *(const float4*)gp;
            areg[2 * i + 1] = *(const float4*)(gp + 4);
        }
    };
    // A: cvt bf16 + swizzled LDS write (slot^(row&7)); compiler waits on areg
    auto writeA = [&]() {
        #pragma unroll
        for (int i = 0; i < 4; ++i) {
            int sidx = tid + i * 512;
            int row = sidx >> 3, sl = sidx & 7;
            float4 f0 = areg[2 * i], f1 = areg[2 * i + 1];
            bf16x8 v;
            v[0] = (bf16_t)f0.x; v[1] = (bf16_t)f0.y; v[2] = (bf16_t)f0.z; v[3] = (bf16_t)f0.w;
            v[4] = (bf16_t)f1.x; v[5] = (bf16_t)f1.y; v[6] = (bf16_t)f1.z; v[7] = (bf16_t)f1.w;
            *(bf16x8*)&As[row * 64 + (sl ^ (row & 7)) * 8] = v;
        }
    };
    // B: 2 x 1KB linear DMA per wave from pre-swizzled Wc tile
    auto issueB = [&](int t, int buf) {
        const bf16_t* src = WcB + (size_t)t * NB_TILE + wv * 1024 + l * 8;
        bf16_t* dst = &Bs[buf][wv * 1024];
        #pragma unroll
        for (int c = 0; c < 2; ++c)
            __builtin_amdgcn_global_load_lds(
                (const AS1 void*)(src + c * 512),
                (AS3 void*)(dst + c * 512), 16, 0, 0);
    };
    auto compute = [&](int buf) {
        #pragma unroll
        for (int kk = 0; kk < 2; ++kk) {
            int sg = kk * 4 + (l >> 4);          // 16B k-slot group (0-conflict)
            bf16x8 af[4], bfr[4];
            #pragma unroll
            for (int fm = 0; fm < 4; ++fm) {
                int row = wm * 64 + fm * 16 + (l & 15);
                af[fm] = *(const bf16x8*)&As[row * 64 + ((sg ^ (row & 7)) * 8)];
            }
            #pragma unroll
            for (int fn = 0; fn < 4; ++fn) {
                int col = wn * 64 + fn * 16 + (l & 15);
                bfr[fn] = *(const bf16x8*)&Bs[buf][col * 64 + ((sg ^ (col & 7)) * 8)];
            }
            #pragma unroll
            for (int fm = 0; fm < 4; ++fm)
                #pragma unroll
                for (int fn = 0; fn < 4; ++fn)
                    acc[fm][fn] = __builtin_amdgcn_mfma_f32_16x16x32_bf16(
                        af[fm], bfr[fn], acc[fm][fn], 0, 0, 0);
        }
    };

    // ---- prologue: fully stage tile 0 (R9 verbatim) ----
    issueB(0, 0);
    FENCE;                               // pin DMA-before-A-loads issue order
    issueA(0);
    FENCE;
    writeA();                            // waits vmcnt for areg automatically
    asm volatile("s_waitcnt vmcnt(0) lgkmcnt(0)" ::: "memory");
    __builtin_amdgcn_s_barrier();

    #pragma unroll
    for (int t = 0; t < NKT; ++t) {
        const int cur = t & 1;
        if (t + 1 < NKT) {
            issueB(t + 1, cur ^ 1);      // DMA -> other B buffer, flies during compute
            FENCE;
            issueA(t + 1);               // 8 loads -> regs, fly during compute
            FENCE;
        }
        compute(cur);
        if (t + 1 < NKT) {
            __builtin_amdgcn_s_barrier();    // all waves done reading As(t)
            writeA();                        // regs (landed during compute) -> As
            asm volatile("s_waitcnt vmcnt(0) lgkmcnt(0)" ::: "memory");
            __builtin_amdgcn_s_barrier();    // As(t+1) + Bs[cur^1](t+1) ready
        }
    }

    // ---- epilogue: gate + reduce (HW exp: v_exp_f32) ----
    // C/D 16x16: col = l&15, row = (l>>4)*4 + e. fn pairs (2q,2q+1) hold V/U
    // logits for the SAME orig output o in the SAME lane.
    const int c16 = l & 15;
    float vb[2], ub[2], wf[2];
    #pragma unroll
    for (int q = 0; q < 2; ++q) {
        int o = (nb * 4 + wn * 2 + q) * 16 + c16;
        vb[q] = Vb[o]; ub[q] = Ub[o]; wf[q] = ww[o];
    }
    const int slot = nb * 2 + wn;                // 8 disjoint partial slots
    #pragma unroll
    for (int fm = 0; fm < 4; ++fm) {
        #pragma unroll
        for (int e = 0; e < 4; ++e) {
            float partial = 0.f;
            #pragma unroll
            for (int q = 0; q < 2; ++q) {
                float zv = acc[fm][2 * q][e] + vb[q];
                float zu = acc[fm][2 * q + 1][e] + ub[q];
                float th = 1.f - 2.f / (__expf(2.f * zv) + 1.f);   // tanh(zv)
                float sg = 1.f / (1.f + __expf(-zu));              // sigmoid(zu)
                partial += th * sg * wf[q];
            }
            partial += __shfl_xor(partial, 1);
            partial += __shfl_xor(partial, 2);
            partial += __shfl_xor(partial, 4);
            partial += __shfl_xor(partial, 8);
            if (c16 == 0) {
                int r = row0 + wm * 64 + fm * 16 + (l >> 4) * 4 + e;
                part[(size_t)slot * M_TOTAL + r] = partial;
            }
        }
    }
}

// ---------------- per-bag masked softmax ----------------
__global__ __launch_bounds__(1024)
void softmax_kernel(const float* __restrict__ part, const int* __restrict__ nonpad,
                    float* __restrict__ out) {
    __shared__ float satt[PZ];
    __shared__ float red[16];
    int b = blockIdx.x;
    int np = nonpad[b];
    int tid = threadIdx.x;

    for (int p = tid; p < PZ; p += 1024) {
        float s = 0.f;
        #pragma unroll
        for (int q = 0; q < 8; ++q) s += part[(size_t)q * M_TOTAL + b * PZ + p];
        satt[p] = s;
    }
    __syncthreads();

    float m = -3.4e38f;
    for (int p = tid; p < np; p += 1024) m = fmaxf(m, satt[p]);
    #pragma unroll
    for (int off = 32; off; off >>= 1) m = fmaxf(m, __shfl_xor(m, off));
    if ((tid & 63) == 0) red[tid >> 6] = m;
    __syncthreads();
    m = red[0];
    #pragma unroll
    for (int i = 1; i < 16; ++i) m = fmaxf(m, red[i]);
    __syncthreads();

    float sum = 0.f;
    for (int p = tid; p < np; p += 1024) sum += __expf(satt[p] - m);
    #pragma unroll
    for (int off = 32; off; off >>= 1) sum += __shfl_xor(sum, off);
    if ((tid & 63) == 0) red[tid >> 6] = sum;
    __syncthreads();
    float S = red[0];
    #pragma unroll
    for (int i = 1; i < 16; ++i) S += red[i];
    float inv = 1.f / S;

    for (int p = tid; p < PZ; p += 1024)
        out[b * PZ + p] = (p < np) ? __expf(satt[p] - m) * inv : 0.f;
}

extern "C" void kernel_launch(void* const* d_in, const int* in_sizes, int n_in,
                              void* d_out, int out_size, void* d_ws, size_t ws_size,
                              hipStream_t stream) {
    const float* x    = (const float*)d_in[0];
    const int* nonpad = (const int*)d_in[1];
    const float* V_w  = (const float*)d_in[2];
    const float* V_b  = (const float*)d_in[3];
    const float* U_w  = (const float*)d_in[4];
    const float* U_b  = (const float*)d_in[5];
    const float* w_w  = (const float*)d_in[6];
    // d_in[7] = w_b: uniform logit shift -> softmax-invariant, unused.

    bf16_t* Wc  = (bf16_t*)d_ws;                                  // 768 KB
    float* part = (float*)((char*)d_ws + (size_t)512 * FZ * 2);   // 2 MB
    float* out  = (float*)d_out;

    pack_weights<<<512, 128, 0, stream>>>(V_w, U_w, Wc);
    gemm_gate<<<1024, 512, 0, stream>>>(x, Wc, V_b, U_b, w_w, part);
    softmax_kernel<<<8, 1024, 0, stream>>>(part, nonpad, out);
}

// Round 14
// 102.317 us; speedup vs baseline: 1.5381x; 1.5116x over previous
//
#include <hip/hip_runtime.h>
#include <hip/hip_bf16.h>
#include <cmath>

#define BZ 8
#define PZ 8192
#define FZ 768
#define FI 256
#define M_TOTAL (BZ * PZ)   // 65536
#define BM 128
#define BK 64
#define NKT (FZ / BK)       // 12
#define NB_TILE (128 * BK)  // 8192 elements = 16 KB per (nb, t) B-tile

typedef __bf16 bf16_t;
typedef __bf16 bf16x8 __attribute__((ext_vector_type(8)));
typedef float f32x4 __attribute__((ext_vector_type(4)));

#define AS1 __attribute__((address_space(1)))
#define AS3 __attribute__((address_space(3)))
#define FENCE asm volatile("" ::: "memory")

// ---------------- pack V_w / U_w into per-(nb,t)-tiled, pre-swizzled bf16 ----
// packed col pr = 32*j + 16*u + r  <->  orig o = 16*j + r  (u: 0=V, 1=U)
// Tile (nb = pr>>7, t): contiguous 16 KB; within it, row prl = pr&127,
// 16B-slot `slot` stored at phys slot^(prl&7)  ->  a LINEAR DMA copy into LDS
// yields the bank-conflict-free swizzled layout directly. (R6-R9 proven)
__global__ void pack_weights(const float* __restrict__ Vw,
                             const float* __restrict__ Uw,
                             bf16_t* __restrict__ Wc) {
    int pr = blockIdx.x;                 // 0..511
    int j = pr >> 5, u = (pr >> 4) & 1, r = pr & 15;
    const float* src = (u ? Uw : Vw) + (size_t)(j * 16 + r) * FZ;
    int nb = pr >> 7, prl = pr & 127;
    for (int k = threadIdx.x; k < FZ; k += blockDim.x) {
        int t = k >> 6, slot = (k >> 3) & 7, jj = k & 7;
        Wc[(size_t)(nb * NKT + t) * NB_TILE + prl * 64 + ((slot ^ (prl & 7)) * 8 + jj)]
            = (bf16_t)src[k];
    }
}

// ---------------- fused GEMM + gate + w-reduce -> partial logits ----------------
// 2048 blocks x 256 threads (4 waves, 2wm x 2wn; wave tile 64x64 = 4fm x 4fn of
// 16x16x32 frags). R9 skeleton (As 16KB + Bs 2x16KB, 3 blocks/CU, VGPR ~80)
// RE-SEQUENCED so no mid-loop drain hits vmcnt(0):
//   tile t: compute(t) | barrier | writeA(t+1) [implicit vmcnt(4): A(t+1) done,
//   B(t+1) rides] | issueA(t+2) into freed areg | vmcnt(8)+lgkm(0) [drains
//   B(t+1), A(t+2) rides across barrier] | barrier | issueB(t+2) into buffer
//   freed 2 barriers + a mem-clobber ago.
// A window ~= full tile (depth-2 timing, single areg set). B window ~= full tile.
__global__ __launch_bounds__(256, 3)
void gemm_gate(const float* __restrict__ x, const bf16_t* __restrict__ Wc,
               const float* __restrict__ Vb, const float* __restrict__ Ub,
               const float* __restrict__ ww, float* __restrict__ part) {
    __shared__ bf16_t As[BM * BK] __attribute__((aligned(16)));      // 16 KB
    __shared__ bf16_t Bs[2][128 * BK] __attribute__((aligned(16)));  // 2x16 KB

    // XCD-aware remap (R2-proven): 4 n-blocks of one m-tile share bid%8 -> same
    // XCD L2 -> x fetched from HBM ~once.
    const int bid = blockIdx.x;
    const int nb = (bid >> 3) & 3;
    const int mt = (bid & 7) | ((bid >> 5) << 3);    // 0..511
    const int tid = threadIdx.x;
    const int l = tid & 63, wv = tid >> 6;
    const int wm = wv >> 1, wn = wv & 1;             // 2M x 2N waves
    const int row0 = mt * BM;

    f32x4 acc[4][4] = {};                            // [fm][fn]
    float4 areg[8];                                  // single A staging set
    const bf16_t* WcB = Wc + (size_t)nb * NKT * NB_TILE;

    // A: issue 8 x dwordx4 fp32 loads for tile t (coalesced)
    auto issueA = [&](int t) {
        #pragma unroll
        for (int i = 0; i < 4; ++i) {
            int sidx = tid + i * 256;            // 0..1023
            int row = sidx >> 3, sl = sidx & 7;
            const float* gp = x + (size_t)(row0 + row) * FZ + t * BK + sl * 8;
            areg[2 * i]     = *(const float4*)gp;
            areg[2 * i + 1] = *(const float4*)(gp + 4);
        }
    };
    // A: cvt bf16 + swizzled LDS write (slot^(row&7)); compiler inserts the
    // (counted) vmcnt wait for areg automatically.
    auto writeA = [&]() {
        #pragma unroll
        for (int i = 0; i < 4; ++i) {
            int sidx = tid + i * 256;
            int row = sidx >> 3, sl = sidx & 7;
            float4 f0 = areg[2 * i], f1 = areg[2 * i + 1];
            bf16x8 v;
            v[0] = (bf16_t)f0.x; v[1] = (bf16_t)f0.y; v[2] = (bf16_t)f0.z; v[3] = (bf16_t)f0.w;
            v[4] = (bf16_t)f1.x; v[5] = (bf16_t)f1.y; v[6] = (bf16_t)f1.z; v[7] = (bf16_t)f1.w;
            *(bf16x8*)&As[row * 64 + (sl ^ (row & 7)) * 8] = v;
        }
    };
    // B: 4 x 1KB linear DMA per wave from pre-swizzled Wc tile
    auto issueB = [&](int t, int buf) {
        const bf16_t* src = WcB + (size_t)t * NB_TILE + wv * 2048 + l * 8;
        bf16_t* dst = &Bs[buf][wv * 2048];
        #pragma unroll
        for (int c = 0; c < 4; ++c)
            __builtin_amdgcn_global_load_lds(
                (const AS1 void*)(src + c * 512),
                (AS3 void*)(dst + c * 512), 16, 0, 0);
    };
    auto compute = [&](int buf) {
        #pragma unroll
        for (int kk = 0; kk < 2; ++kk) {
            int sg = kk * 4 + (l >> 4);          // 16B k-slot group (0-conflict)
            bf16x8 af[4], bfr[4];
            #pragma unroll
            for (int fm = 0; fm < 4; ++fm) {
                int row = wm * 64 + fm * 16 + (l & 15);
                af[fm] = *(const bf16x8*)&As[row * 64 + ((sg ^ (row & 7)) * 8)];
            }
            #pragma unroll
            for (int fn = 0; fn < 4; ++fn) {
                int col = wn * 64 + fn * 16 + (l & 15);
                bfr[fn] = *(const bf16x8*)&Bs[buf][col * 64 + ((sg ^ (col & 7)) * 8)];
            }
            #pragma unroll
            for (int fm = 0; fm < 4; ++fm)
                #pragma unroll
                for (int fn = 0; fn < 4; ++fn)
                    acc[fm][fn] = __builtin_amdgcn_mfma_f32_16x16x32_bf16(
                        af[fm], bfr[fn], acc[fm][fn], 0, 0, 0);
        }
    };

    // ---- prologue ----
    issueB(0, 0); FENCE;                 // FIFO: B(0)
    issueA(0);    FENCE;                 // FIFO: B(0), A(0)
    writeA();                            // implicit wait drains A(0) (and B(0))
    issueA(1);    FENCE;                 // A(1) flies
    asm volatile("s_waitcnt lgkmcnt(0)" ::: "memory");   // ds_writes of As(0)
    __builtin_amdgcn_sched_barrier(0);
    __builtin_amdgcn_s_barrier();        // As(0), Bs[0] ready
    issueB(1, 1); FENCE;                 // B(1) flies; FIFO: A(1), B(1)

    #pragma unroll
    for (int t = 0; t < NKT; ++t) {
        const int cur = t & 1;
        compute(cur);                    // reads As(t), Bs[cur]; A(t+1)/B(t+1) fly
        if (t + 1 < NKT) {
            __builtin_amdgcn_s_barrier();    // all waves done reading As(t)/Bs[cur]
            writeA();                        // implicit vmcnt(4): A(t+1) done,
                                             // B(t+1) rides through cvt+ds_write
            if (t + 2 < NKT) { issueA(t + 2); FENCE; }   // recycle areg; A(t+2) flies
            if (t + 2 < NKT)
                // drain B(t+1) (oldest remaining); A(t+2)[8] rides across barrier
                asm volatile("s_waitcnt vmcnt(8) lgkmcnt(0)" ::: "memory");
            else
                asm volatile("s_waitcnt vmcnt(0) lgkmcnt(0)" ::: "memory");
            __builtin_amdgcn_sched_barrier(0);
            __builtin_amdgcn_s_barrier();    // As(t+1) + Bs[cur^1](t+1) ready
            if (t + 2 < NKT) { issueB(t + 2, cur); FENCE; }  // buffer freed 2
                                             // barriers + mem-clobber ago; safe
        }
    }

    // ---- epilogue: gate + reduce (HW exp: v_exp_f32) ----
    // C/D 16x16: col = l&15, row = (l>>4)*4 + e. fn pairs (2q,2q+1) hold V/U
    // logits for the SAME orig output o in the SAME lane.
    const int c16 = l & 15;
    float vb[2], ub[2], wf[2];
    #pragma unroll
    for (int q = 0; q < 2; ++q) {
        int o = (nb * 4 + wn * 2 + q) * 16 + c16;
        vb[q] = Vb[o]; ub[q] = Ub[o]; wf[q] = ww[o];
    }
    const int slot = nb * 2 + wn;                // 8 disjoint partial slots
    #pragma unroll
    for (int fm = 0; fm < 4; ++fm) {
        #pragma unroll
        for (int e = 0; e < 4; ++e) {
            float partial = 0.f;
            #pragma unroll
            for (int q = 0; q < 2; ++q) {
                float zv = acc[fm][2 * q][e] + vb[q];
                float zu = acc[fm][2 * q + 1][e] + ub[q];
                float th = 1.f - 2.f / (__expf(2.f * zv) + 1.f);   // tanh(zv)
                float sg = 1.f / (1.f + __expf(-zu));              // sigmoid(zu)
                partial += th * sg * wf[q];
            }
            partial += __shfl_xor(partial, 1);
            partial += __shfl_xor(partial, 2);
            partial += __shfl_xor(partial, 4);
            partial += __shfl_xor(partial, 8);
            if (c16 == 0) {
                int r = row0 + wm * 64 + fm * 16 + (l >> 4) * 4 + e;
                part[(size_t)slot * M_TOTAL + r] = partial;
            }
        }
    }
}

// ---------------- per-bag masked softmax ----------------
__global__ __launch_bounds__(1024)
void softmax_kernel(const float* __restrict__ part, const int* __restrict__ nonpad,
                    float* __restrict__ out) {
    __shared__ float satt[PZ];
    __shared__ float red[16];
    int b = blockIdx.x;
    int np = nonpad[b];
    int tid = threadIdx.x;

    for (int p = tid; p < PZ; p += 1024) {
        float s = 0.f;
        #pragma unroll
        for (int q = 0; q < 8; ++q) s += part[(size_t)q * M_TOTAL + b * PZ + p];
        satt[p] = s;
    }
    __syncthreads();

    float m = -3.4e38f;
    for (int p = tid; p < np; p += 1024) m = fmaxf(m, satt[p]);
    #pragma unroll
    for (int off = 32; off; off >>= 1) m = fmaxf(m, __shfl_xor(m, off));
    if ((tid & 63) == 0) red[tid >> 6] = m;
    __syncthreads();
    m = red[0];
    #pragma unroll
    for (int i = 1; i < 16; ++i) m = fmaxf(m, red[i]);
    __syncthreads();

    float sum = 0.f;
    for (int p = tid; p < np; p += 1024) sum += __expf(satt[p] - m);
    #pragma unroll
    for (int off = 32; off; off >>= 1) sum += __shfl_xor(sum, off);
    if ((tid & 63) == 0) red[tid >> 6] = sum;
    __syncthreads();
    float S = red[0];
    #pragma unroll
    for (int i = 1; i < 16; ++i) S += red[i];
    float inv = 1.f / S;

    for (int p = tid; p < PZ; p += 1024)
        out[b * PZ + p] = (p < np) ? __expf(satt[p] - m) * inv : 0.f;
}

extern "C" void kernel_launch(void* const* d_in, const int* in_sizes, int n_in,
                              void* d_out, int out_size, void* d_ws, size_t ws_size,
                              hipStream_t stream) {
    const float* x    = (const float*)d_in[0];
    const int* nonpad = (const int*)d_in[1];
    const float* V_w  = (const float*)d_in[2];
    const float* V_b  = (const float*)d_in[3];
    const float* U_w  = (const float*)d_in[4];
    const float* U_b  = (const float*)d_in[5];
    const float* w_w  = (const float*)d_in[6];
    // d_in[7] = w_b: uniform logit shift -> softmax-invariant, unused.

    bf16_t* Wc  = (bf16_t*)d_ws;                                  // 768 KB
    float* part = (float*)((char*)d_ws + (size_t)512 * FZ * 2);   // 2 MB
    float* out  = (float*)d_out;

    pack_weights<<<512, 128, 0, stream>>>(V_w, U_w, Wc);
    gemm_gate<<<2048, 256, 0, stream>>>(x, Wc, V_b, U_b, w_w, part);
    softmax_kernel<<<8, 1024, 0, stream>>>(part, nonpad, out);
}

// Round 15
// 89.628 us; speedup vs baseline: 1.7559x; 1.1416x over previous
//
#include <hip/hip_runtime.h>
#include <hip/hip_bf16.h>
#include <cmath>

#define BZ 8
#define PZ 8192
#define FZ 768
#define FI 256
#define M_TOTAL (BZ * PZ)   // 65536
#define BM 128
#define BK 64
#define NKT (FZ / BK)       // 12
#define NB_TILE (128 * BK)  // 8192 elements = 16 KB per (nb, t) B-tile

typedef __bf16 bf16_t;
typedef __bf16 bf16x8 __attribute__((ext_vector_type(8)));
typedef float f32x4 __attribute__((ext_vector_type(4)));

#define AS1 __attribute__((address_space(1)))
#define AS3 __attribute__((address_space(3)))
#define FENCE asm volatile("" ::: "memory")

// ---------------- pack V_w / U_w into per-(nb,t)-tiled, pre-swizzled bf16 ----
// packed col pr = 32*j + 16*u + r  <->  orig o = 16*j + r  (u: 0=V, 1=U)
// Tile (nb = pr>>7, t): contiguous 16 KB; within it, row prl = pr&127,
// 16B-slot `slot` stored at phys slot^(prl&7)  ->  a LINEAR DMA copy into LDS
// yields the bank-conflict-free swizzled layout directly. (R6-R9 proven)
__global__ void pack_weights(const float* __restrict__ Vw,
                             const float* __restrict__ Uw,
                             bf16_t* __restrict__ Wc) {
    int pr = blockIdx.x;                 // 0..511
    int j = pr >> 5, u = (pr >> 4) & 1, r = pr & 15;
    const float* src = (u ? Uw : Vw) + (size_t)(j * 16 + r) * FZ;
    int nb = pr >> 7, prl = pr & 127;
    for (int k = threadIdx.x; k < FZ; k += blockDim.x) {
        int t = k >> 6, slot = (k >> 3) & 7, jj = k & 7;
        Wc[(size_t)(nb * NKT + t) * NB_TILE + prl * 64 + ((slot ^ (prl & 7)) * 8 + jj)]
            = (bf16_t)src[k];
    }
}

// ---------------- fused GEMM + gate + w-reduce -> partial logits ----------------
// R9 champion (94 us wall) VERBATIM: 2048 blocks x 256 threads (4 waves,
// 2wm x 2wn; wave tile 64x64 = 4fm x 4fn of 16x16x32 frags). Single As 16KB +
// double Bs 2x16KB = 48KB -> 3 blocks/CU (12 waves). Distance-1 prefetch:
// issue B(t+1) DMA + A(t+1) reg loads BEFORE compute(t); barrier; writeA
// (implicit full drain); vmcnt(0); barrier.
__global__ __launch_bounds__(256, 3)
void gemm_gate(const float* __restrict__ x, const bf16_t* __restrict__ Wc,
               const float* __restrict__ Vb, const float* __restrict__ Ub,
               const float* __restrict__ ww, float* __restrict__ part) {
    __shared__ bf16_t As[BM * BK] __attribute__((aligned(16)));      // 16 KB
    __shared__ bf16_t Bs[2][128 * BK] __attribute__((aligned(16)));  // 2x16 KB

    // XCD-aware remap (R2-proven): 4 n-blocks of one m-tile share bid%8 -> same
    // XCD L2 -> x fetched from HBM ~once.
    const int bid = blockIdx.x;
    const int nb = (bid >> 3) & 3;
    const int mt = (bid & 7) | ((bid >> 5) << 3);    // 0..511
    const int tid = threadIdx.x;
    const int l = tid & 63, wv = tid >> 6;
    const int wm = wv >> 1, wn = wv & 1;             // 2M x 2N waves
    const int row0 = mt * BM;

    f32x4 acc[4][4] = {};                            // [fm][fn]
    float4 areg[8];                                  // A(t+1) staging regs
    const bf16_t* WcB = Wc + (size_t)nb * NKT * NB_TILE;

    auto issueA = [&](int t) {
        #pragma unroll
        for (int i = 0; i < 4; ++i) {
            int sidx = tid + i * 256;            // 0..1023
            int row = sidx >> 3, sl = sidx & 7;
            const float* gp = x + (size_t)(row0 + row) * FZ + t * BK + sl * 8;
            areg[2 * i]     = *(const float4*)gp;
            areg[2 * i + 1] = *(const float4*)(gp + 4);
        }
    };
    auto writeA = [&]() {
        #pragma unroll
        for (int i = 0; i < 4; ++i) {
            int sidx = tid + i * 256;
            int row = sidx >> 3, sl = sidx & 7;
            float4 f0 = areg[2 * i], f1 = areg[2 * i + 1];
            bf16x8 v;
            v[0] = (bf16_t)f0.x; v[1] = (bf16_t)f0.y; v[2] = (bf16_t)f0.z; v[3] = (bf16_t)f0.w;
            v[4] = (bf16_t)f1.x; v[5] = (bf16_t)f1.y; v[6] = (bf16_t)f1.z; v[7] = (bf16_t)f1.w;
            *(bf16x8*)&As[row * 64 + (sl ^ (row & 7)) * 8] = v;
        }
    };
    auto issueB = [&](int t, int buf) {
        const bf16_t* src = WcB + (size_t)t * NB_TILE + wv * 2048 + l * 8;
        bf16_t* dst = &Bs[buf][wv * 2048];
        #pragma unroll
        for (int c = 0; c < 4; ++c)
            __builtin_amdgcn_global_load_lds(
                (const AS1 void*)(src + c * 512),
                (AS3 void*)(dst + c * 512), 16, 0, 0);
    };
    auto compute = [&](int buf) {
        #pragma unroll
        for (int kk = 0; kk < 2; ++kk) {
            int sg = kk * 4 + (l >> 4);          // 16B k-slot group (0-conflict)
            bf16x8 af[4], bfr[4];
            #pragma unroll
            for (int fm = 0; fm < 4; ++fm) {
                int row = wm * 64 + fm * 16 + (l & 15);
                af[fm] = *(const bf16x8*)&As[row * 64 + ((sg ^ (row & 7)) * 8)];
            }
            #pragma unroll
            for (int fn = 0; fn < 4; ++fn) {
                int col = wn * 64 + fn * 16 + (l & 15);
                bfr[fn] = *(const bf16x8*)&Bs[buf][col * 64 + ((sg ^ (col & 7)) * 8)];
            }
            #pragma unroll
            for (int fm = 0; fm < 4; ++fm)
                #pragma unroll
                for (int fn = 0; fn < 4; ++fn)
                    acc[fm][fn] = __builtin_amdgcn_mfma_f32_16x16x32_bf16(
                        af[fm], bfr[fn], acc[fm][fn], 0, 0, 0);
        }
    };

    // ---- prologue: fully stage tile 0 ----
    issueB(0, 0);
    FENCE;                               // pin DMA-before-A-loads issue order
    issueA(0);
    FENCE;
    writeA();                            // waits vmcnt for areg automatically
    asm volatile("s_waitcnt vmcnt(0) lgkmcnt(0)" ::: "memory");
    __builtin_amdgcn_s_barrier();

    #pragma unroll
    for (int t = 0; t < NKT; ++t) {
        const int cur = t & 1;
        if (t + 1 < NKT) {
            issueB(t + 1, cur ^ 1);      // DMA -> other B buffer, flies during compute
            FENCE;
            issueA(t + 1);               // 8 loads -> regs, fly during compute
            FENCE;
        }
        compute(cur);
        if (t + 1 < NKT) {
            __builtin_amdgcn_s_barrier();    // all waves done reading As(t)
            writeA();                        // regs (landed during compute) -> As
            asm volatile("s_waitcnt vmcnt(0) lgkmcnt(0)" ::: "memory");
            __builtin_amdgcn_s_barrier();    // As(t+1) + Bs[cur^1](t+1) ready
        }
    }

    // ---- epilogue: gate + reduce (HW exp: v_exp_f32) ----
    const int c16 = l & 15;
    float vb[2], ub[2], wf[2];
    #pragma unroll
    for (int q = 0; q < 2; ++q) {
        int o = (nb * 4 + wn * 2 + q) * 16 + c16;
        vb[q] = Vb[o]; ub[q] = Ub[o]; wf[q] = ww[o];
    }
    const int slot = nb * 2 + wn;                // 8 disjoint partial slots
    #pragma unroll
    for (int fm = 0; fm < 4; ++fm) {
        #pragma unroll
        for (int e = 0; e < 4; ++e) {
            float partial = 0.f;
            #pragma unroll
            for (int q = 0; q < 2; ++q) {
                float zv = acc[fm][2 * q][e] + vb[q];
                float zu = acc[fm][2 * q + 1][e] + ub[q];
                float th = 1.f - 2.f / (__expf(2.f * zv) + 1.f);   // tanh(zv)
                float sg = 1.f / (1.f + __expf(-zu));              // sigmoid(zu)
                partial += th * sg * wf[q];
            }
            partial += __shfl_xor(partial, 1);
            partial += __shfl_xor(partial, 2);
            partial += __shfl_xor(partial, 4);
            partial += __shfl_xor(partial, 8);
            if (c16 == 0) {
                int r = row0 + wm * 64 + fm * 16 + (l >> 4) * 4 + e;
                part[(size_t)slot * M_TOTAL + r] = partial;
            }
        }
    }
}

// ---------------- softmax stage 1: per-chunk stats (64 blocks) ----------------
// block = (b, c): chunk c of 1024 positions in bag b. Sum the 8 partial slots,
// store the logit to satt_ws, and compute masked chunk max + sum of exp.
__global__ __launch_bounds__(1024)
void softmax_part(const float* __restrict__ part, const int* __restrict__ nonpad,
                  float* __restrict__ satt, float* __restrict__ stats) {
    __shared__ float red[16];
    const int b = blockIdx.x >> 3, c = blockIdx.x & 7;
    const int np = nonpad[b];
    const int p = c * 1024 + threadIdx.x;        // one position per thread
    const int tid = threadIdx.x;

    float s = 0.f;
    #pragma unroll
    for (int q = 0; q < 8; ++q) s += part[(size_t)q * M_TOTAL + b * PZ + p];
    satt[b * PZ + p] = s;
    const bool valid = p < np;

    // block max over valid lanes
    float m = valid ? s : -3.4e38f;
    #pragma unroll
    for (int off = 32; off; off >>= 1) m = fmaxf(m, __shfl_xor(m, off));
    if ((tid & 63) == 0) red[tid >> 6] = m;
    __syncthreads();
    m = red[0];
    #pragma unroll
    for (int i = 1; i < 16; ++i) m = fmaxf(m, red[i]);
    __syncthreads();

    // block sum of exp(s - m) over valid lanes
    float e = valid ? __expf(s - m) : 0.f;
    #pragma unroll
    for (int off = 32; off; off >>= 1) e += __shfl_xor(e, off);
    if ((tid & 63) == 0) red[tid >> 6] = e;
    __syncthreads();
    if (tid == 0) {
        float S = red[0];
        #pragma unroll
        for (int i = 1; i < 16; ++i) S += red[i];
        stats[(b * 8 + c) * 2 + 0] = m;
        stats[(b * 8 + c) * 2 + 1] = S;
    }
}

// ---------------- softmax stage 2: merge chunk stats (8 blocks) ----------------
__global__ __launch_bounds__(64)
void softmax_merge(const float* __restrict__ stats, float* __restrict__ g) {
    const int b = blockIdx.x;
    const int l = threadIdx.x;
    float m = (l < 8) ? stats[(b * 8 + l) * 2 + 0] : -3.4e38f;
    float s = (l < 8) ? stats[(b * 8 + l) * 2 + 1] : 0.f;
    float M = m;
    #pragma unroll
    for (int off = 4; off; off >>= 1) M = fmaxf(M, __shfl_xor(M, off));
    float contrib = s * __expf(m - M);           // exp(-inf)=0 kills empty chunks
    #pragma unroll
    for (int off = 4; off; off >>= 1) contrib += __shfl_xor(contrib, off);
    if (l == 0) {
        g[b * 2 + 0] = M;
        g[b * 2 + 1] = 1.f / contrib;
    }
}

// ---------------- softmax stage 3: scale + write (64 blocks) ----------------
__global__ __launch_bounds__(1024)
void softmax_write(const float* __restrict__ satt, const float* __restrict__ g,
                   const int* __restrict__ nonpad, float* __restrict__ out) {
    const int b = blockIdx.x >> 3, c = blockIdx.x & 7;
    const int np = nonpad[b];
    const int p = c * 1024 + threadIdx.x;
    const float M = g[b * 2 + 0], inv = g[b * 2 + 1];
    const float s = satt[b * PZ + p];
    out[b * PZ + p] = (p < np) ? __expf(s - M) * inv : 0.f;
}

extern "C" void kernel_launch(void* const* d_in, const int* in_sizes, int n_in,
                              void* d_out, int out_size, void* d_ws, size_t ws_size,
                              hipStream_t stream) {
    const float* x    = (const float*)d_in[0];
    const int* nonpad = (const int*)d_in[1];
    const float* V_w  = (const float*)d_in[2];
    const float* V_b  = (const float*)d_in[3];
    const float* U_w  = (const float*)d_in[4];
    const float* U_b  = (const float*)d_in[5];
    const float* w_w  = (const float*)d_in[6];
    // d_in[7] = w_b: uniform logit shift -> softmax-invariant, unused.

    char* wsp = (char*)d_ws;
    bf16_t* Wc   = (bf16_t*)wsp;                          wsp += (size_t)512 * FZ * 2;   // 768 KB
    float* part  = (float*)wsp;                           wsp += (size_t)8 * M_TOTAL * 4; // 2 MB
    float* satt  = (float*)wsp;                           wsp += (size_t)M_TOTAL * 4;     // 256 KB
    float* stats = (float*)wsp;                           wsp += 64 * 2 * 4;              // 512 B
    float* g     = (float*)wsp;
    float* out   = (float*)d_out;

    pack_weights<<<512, 128, 0, stream>>>(V_w, U_w, Wc);
    gemm_gate<<<2048, 256, 0, stream>>>(x, Wc, V_b, U_b, w_w, part);
    softmax_part<<<64, 1024, 0, stream>>>(part, nonpad, satt, stats);
    softmax_merge<<<8, 64, 0, stream>>>(stats, g);
    softmax_write<<<64, 1024, 0, stream>>>(satt, g, nonpad, out);
}

// Round 16
// 81.270 us; speedup vs baseline: 1.9365x; 1.1028x over previous
//
#include <hip/hip_runtime.h>
#include <hip/hip_bf16.h>
#include <cmath>

#define BZ 8
#define PZ 8192
#define FZ 768
#define FI 256
#define M_TOTAL (BZ * PZ)   // 65536
#define BM 128
#define BN 256
#define BK 64
#define NKT (FZ / BK)       // 12
#define NB_TILE (BN * BK)   // 16384 elements = 32 KB per (nb, t) B-tile

typedef __bf16 bf16_t;
typedef __bf16 bf16x8 __attribute__((ext_vector_type(8)));
typedef float f32x4 __attribute__((ext_vector_type(4)));

#define AS1 __attribute__((address_space(1)))
#define AS3 __attribute__((address_space(3)))
#define FENCE asm volatile("" ::: "memory")

// ---------------- pack V_w / U_w into per-(nb,t)-tiled, pre-swizzled bf16 ----
// packed col pr = 32*j + 16*u + r  <->  orig o = 16*j + r  (u: 0=V, 1=U)
// Tile (nb = pr>>8, t): contiguous 32 KB; within it, row prl = pr&255,
// 16B-slot `slot` stored at phys slot^(prl&7)  ->  a LINEAR DMA copy into LDS
// yields the bank-conflict-free swizzled layout directly.
__global__ void pack_weights(const float* __restrict__ Vw,
                             const float* __restrict__ Uw,
                             bf16_t* __restrict__ Wc) {
    int pr = blockIdx.x;                 // 0..511
    int j = pr >> 5, u = (pr >> 4) & 1, r = pr & 15;
    const float* src = (u ? Uw : Vw) + (size_t)(j * 16 + r) * FZ;
    int nb = pr >> 8, prl = pr & 255;
    for (int k = threadIdx.x; k < FZ; k += blockDim.x) {
        int t = k >> 6, slot = (k >> 3) & 7, jj = k & 7;
        Wc[(size_t)(nb * NKT + t) * NB_TILE + prl * 64 + ((slot ^ (prl & 7)) * 8 + jj)]
            = (bf16_t)src[k];
    }
}

// ---------------- fused GEMM + gate + w-reduce -> partial logits ----------------
// 1024 blocks x 256 threads (4 waves, 2wm x 2wn; WAVE TILE 64x128 = 4fm x 8fn
// of 16x16x32 frags -- 0.375 KB LDS-read per MFMA vs 0.5 at 64x64, and half
// the drain events per MFMA). Sync structure = R15 champion VERBATIM:
// issue B(t+1) DMA + A(t+1) reg loads BEFORE compute(t); barrier; writeA
// (implicit full drain); vmcnt(0); barrier. As 16KB + Bs 2x32KB = 80 KB ->
// 2 blocks/CU (8 waves).
__global__ __launch_bounds__(256, 2)
void gemm_gate(const float* __restrict__ x, const bf16_t* __restrict__ Wc,
               const float* __restrict__ Vb, const float* __restrict__ Ub,
               const float* __restrict__ ww, float* __restrict__ part) {
    __shared__ bf16_t As[BM * BK] __attribute__((aligned(16)));      // 16 KB
    __shared__ bf16_t Bs[2][BN * BK] __attribute__((aligned(16)));   // 2x32 KB

    // XCD-aware remap (R2-proven): the 2 n-blocks of one m-tile share bid%8
    // -> same XCD L2. 1024 = 16 x 64, bijective.
    const int bid = blockIdx.x;
    const int nb = (bid >> 3) & 1;
    const int mt = (bid & 7) | ((bid >> 4) << 3);    // 0..511
    const int tid = threadIdx.x;
    const int l = tid & 63, wv = tid >> 6;
    const int wm = wv >> 1, wn = wv & 1;             // 2M x 2N waves
    const int row0 = mt * BM;

    f32x4 acc[4][8] = {};                            // [fm][fn] 128 VGPR
    float4 areg[8];                                  // A(t+1) staging regs
    const bf16_t* WcB = Wc + (size_t)nb * NKT * NB_TILE;

    // A: issue 8 x dwordx4 fp32 loads for tile t (coalesced) -- R15 verbatim
    auto issueA = [&](int t) {
        #pragma unroll
        for (int i = 0; i < 4; ++i) {
            int sidx = tid + i * 256;            // 0..1023
            int row = sidx >> 3, sl = sidx & 7;
            const float* gp = x + (size_t)(row0 + row) * FZ + t * BK + sl * 8;
            areg[2 * i]     = *(const float4*)gp;
            areg[2 * i + 1] = *(const float4*)(gp + 4);
        }
    };
    // A: cvt bf16 + swizzled LDS write (slot^(row&7)) -- R15 verbatim
    auto writeA = [&]() {
        #pragma unroll
        for (int i = 0; i < 4; ++i) {
            int sidx = tid + i * 256;
            int row = sidx >> 3, sl = sidx & 7;
            float4 f0 = areg[2 * i], f1 = areg[2 * i + 1];
            bf16x8 v;
            v[0] = (bf16_t)f0.x; v[1] = (bf16_t)f0.y; v[2] = (bf16_t)f0.z; v[3] = (bf16_t)f0.w;
            v[4] = (bf16_t)f1.x; v[5] = (bf16_t)f1.y; v[6] = (bf16_t)f1.z; v[7] = (bf16_t)f1.w;
            *(bf16x8*)&As[row * 64 + (sl ^ (row & 7)) * 8] = v;
        }
    };
    // B: 8 x 1KB linear DMA per wave from pre-swizzled Wc tile (32 KB total)
    auto issueB = [&](int t, int buf) {
        const bf16_t* src = WcB + (size_t)t * NB_TILE + wv * 4096 + l * 8;
        bf16_t* dst = &Bs[buf][wv * 4096];
        #pragma unroll
        for (int c = 0; c < 8; ++c)
            __builtin_amdgcn_global_load_lds(
                (const AS1 void*)(src + c * 512),
                (AS3 void*)(dst + c * 512), 16, 0, 0);
    };
    auto compute = [&](int buf) {
        #pragma unroll
        for (int kk = 0; kk < 2; ++kk) {
            int sg = kk * 4 + (l >> 4);          // 16B k-slot group (0-conflict)
            bf16x8 af[4];
            #pragma unroll
            for (int fm = 0; fm < 4; ++fm) {
                int row = wm * 64 + fm * 16 + (l & 15);
                af[fm] = *(const bf16x8*)&As[row * 64 + ((sg ^ (row & 7)) * 8)];
            }
            #pragma unroll
            for (int fn = 0; fn < 8; ++fn) {
                int col = wn * 128 + fn * 16 + (l & 15);
                bf16x8 bfr = *(const bf16x8*)&Bs[buf][col * 64 + ((sg ^ (col & 7)) * 8)];
                #pragma unroll
                for (int fm = 0; fm < 4; ++fm)
                    acc[fm][fn] = __builtin_amdgcn_mfma_f32_16x16x32_bf16(
                        af[fm], bfr, acc[fm][fn], 0, 0, 0);
            }
        }
    };

    // ---- prologue: fully stage tile 0 (R15 verbatim) ----
    issueB(0, 0);
    FENCE;                               // pin DMA-before-A-loads issue order
    issueA(0);
    FENCE;
    writeA();                            // waits vmcnt for areg automatically
    asm volatile("s_waitcnt vmcnt(0) lgkmcnt(0)" ::: "memory");
    __builtin_amdgcn_s_barrier();

    #pragma unroll
    for (int t = 0; t < NKT; ++t) {
        const int cur = t & 1;
        if (t + 1 < NKT) {
            issueB(t + 1, cur ^ 1);      // DMA -> other B buffer, flies during compute
            FENCE;
            issueA(t + 1);               // 8 loads -> regs, fly during compute
            FENCE;
        }
        compute(cur);
        if (t + 1 < NKT) {
            __builtin_amdgcn_s_barrier();    // all waves done reading As(t)
            writeA();                        // regs (landed during compute) -> As
            asm volatile("s_waitcnt vmcnt(0) lgkmcnt(0)" ::: "memory");
            __builtin_amdgcn_s_barrier();    // As(t+1) + Bs[cur^1](t+1) ready
        }
    }

    // ---- epilogue: gate + reduce (HW exp: v_exp_f32) ----
    // C/D 16x16: col = l&15, row = (l>>4)*4 + e. fn pairs (2q,2q+1) hold V/U
    // logits for the SAME orig output o in the SAME lane.
    const int c16 = l & 15;
    float vb[4], ub[4], wf[4];
    #pragma unroll
    for (int q = 0; q < 4; ++q) {
        int o = (nb * 8 + wn * 4 + q) * 16 + c16;
        vb[q] = Vb[o]; ub[q] = Ub[o]; wf[q] = ww[o];
    }
    const int slot = nb * 2 + wn;                // 4 disjoint partial slots
    #pragma unroll
    for (int fm = 0; fm < 4; ++fm) {
        #pragma unroll
        for (int e = 0; e < 4; ++e) {
            float partial = 0.f;
            #pragma unroll
            for (int q = 0; q < 4; ++q) {
                float zv = acc[fm][2 * q][e] + vb[q];
                float zu = acc[fm][2 * q + 1][e] + ub[q];
                float th = 1.f - 2.f / (__expf(2.f * zv) + 1.f);   // tanh(zv)
                float sg = 1.f / (1.f + __expf(-zu));              // sigmoid(zu)
                partial += th * sg * wf[q];
            }
            partial += __shfl_xor(partial, 1);
            partial += __shfl_xor(partial, 2);
            partial += __shfl_xor(partial, 4);
            partial += __shfl_xor(partial, 8);
            if (c16 == 0) {
                int r = row0 + wm * 64 + fm * 16 + (l >> 4) * 4 + e;
                part[(size_t)slot * M_TOTAL + r] = partial;
            }
        }
    }
}

// ---------------- softmax stage 1: per-chunk stats (64 blocks) ----------------
__global__ __launch_bounds__(1024)
void softmax_part(const float* __restrict__ part, const int* __restrict__ nonpad,
                  float* __restrict__ satt, float* __restrict__ stats) {
    __shared__ float red[16];
    const int b = blockIdx.x >> 3, c = blockIdx.x & 7;
    const int np = nonpad[b];
    const int p = c * 1024 + threadIdx.x;        // one position per thread
    const int tid = threadIdx.x;

    float s = 0.f;
    #pragma unroll
    for (int q = 0; q < 4; ++q) s += part[(size_t)q * M_TOTAL + b * PZ + p];
    satt[b * PZ + p] = s;
    const bool valid = p < np;

    float m = valid ? s : -3.4e38f;
    #pragma unroll
    for (int off = 32; off; off >>= 1) m = fmaxf(m, __shfl_xor(m, off));
    if ((tid & 63) == 0) red[tid >> 6] = m;
    __syncthreads();
    m = red[0];
    #pragma unroll
    for (int i = 1; i < 16; ++i) m = fmaxf(m, red[i]);
    __syncthreads();

    float e = valid ? __expf(s - m) : 0.f;
    #pragma unroll
    for (int off = 32; off; off >>= 1) e += __shfl_xor(e, off);
    if ((tid & 63) == 0) red[tid >> 6] = e;
    __syncthreads();
    if (tid == 0) {
        float S = red[0];
        #pragma unroll
        for (int i = 1; i < 16; ++i) S += red[i];
        stats[(b * 8 + c) * 2 + 0] = m;
        stats[(b * 8 + c) * 2 + 1] = S;
    }
}

// ---------------- softmax stage 2: merge chunk stats (8 blocks) ----------------
__global__ __launch_bounds__(64)
void softmax_merge(const float* __restrict__ stats, float* __restrict__ g) {
    const int b = blockIdx.x;
    const int l = threadIdx.x;
    float m = (l < 8) ? stats[(b * 8 + l) * 2 + 0] : -3.4e38f;
    float s = (l < 8) ? stats[(b * 8 + l) * 2 + 1] : 0.f;
    float M = m;
    #pragma unroll
    for (int off = 4; off; off >>= 1) M = fmaxf(M, __shfl_xor(M, off));
    float contrib = s * __expf(m - M);           // exp(-inf)=0 kills empty chunks
    #pragma unroll
    for (int off = 4; off; off >>= 1) contrib += __shfl_xor(contrib, off);
    if (l == 0) {
        g[b * 2 + 0] = M;
        g[b * 2 + 1] = 1.f / contrib;
    }
}

// ---------------- softmax stage 3: scale + write (64 blocks) ----------------
__global__ __launch_bounds__(1024)
void softmax_write(const float* __restrict__ satt, const float* __restrict__ g,
                   const int* __restrict__ nonpad, float* __restrict__ out) {
    const int b = blockIdx.x >> 3, c = blockIdx.x & 7;
    const int np = nonpad[b];
    const int p = c * 1024 + threadIdx.x;
    const float M = g[b * 2 + 0], inv = g[b * 2 + 1];
    const float s = satt[b * PZ + p];
    out[b * PZ + p] = (p < np) ? __expf(s - M) * inv : 0.f;
}

extern "C" void kernel_launch(void* const* d_in, const int* in_sizes, int n_in,
                              void* d_out, int out_size, void* d_ws, size_t ws_size,
                              hipStream_t stream) {
    const float* x    = (const float*)d_in[0];
    const int* nonpad = (const int*)d_in[1];
    const float* V_w  = (const float*)d_in[2];
    const float* V_b  = (const float*)d_in[3];
    const float* U_w  = (const float*)d_in[4];
    const float* U_b  = (const float*)d_in[5];
    const float* w_w  = (const float*)d_in[6];
    // d_in[7] = w_b: uniform logit shift -> softmax-invariant, unused.

    char* wsp = (char*)d_ws;
    bf16_t* Wc   = (bf16_t*)wsp;                wsp += (size_t)512 * FZ * 2;    // 768 KB
    float* part  = (float*)wsp;                 wsp += (size_t)4 * M_TOTAL * 4; // 1 MB
    float* satt  = (float*)wsp;                 wsp += (size_t)M_TOTAL * 4;     // 256 KB
    float* stats = (float*)wsp;                 wsp += 64 * 2 * 4;              // 512 B
    float* g     = (float*)wsp;
    float* out   = (float*)d_out;

    pack_weights<<<512, 128, 0, stream>>>(V_w, U_w, Wc);
    gemm_gate<<<1024, 256, 0, stream>>>(x, Wc, V_b, U_b, w_w, part);
    softmax_part<<<64, 1024, 0, stream>>>(part, nonpad, satt, stats);
    softmax_merge<<<8, 64, 0, stream>>>(stats, g);
    softmax_write<<<64, 1024, 0, stream>>>(satt, g, nonpad, out);
}